// Round 6
// baseline (2342.520 us; speedup 1.0000x reference)
//
#include <hip/hip_runtime.h>

typedef unsigned short u16;
typedef unsigned int   u32;
typedef short bf16x8 __attribute__((ext_vector_type(8)));
typedef float f32x4  __attribute__((ext_vector_type(4)));

#define V_ 780
#define N_ 50000
#define M_ 100001
#define K_ 6
#define H_ 256
#define B_ 64
#define DEPTH_ 6

// hE packed row: 512 u16 = 64 chunks of 16 B; chunk c = [h(4c..4c+3)|E(4c..4c+3)].
// One 16 B load fetches a lane's h AND E slice -> halves gather request count.
#define HE_LD 512

typedef __attribute__((address_space(3))) u32 lds_u32;
typedef __attribute__((address_space(1))) const u32 glb_u32;
__device__ __forceinline__ void dma16(const void* g, void* l){
  __builtin_amdgcn_global_load_lds((glb_u32*)g, (lds_u32*)l, 16, 0, 0);
}

__device__ __forceinline__ float b2f(u16 u){
  union { u32 i; float f; } x; x.i = ((u32)u) << 16; return x.f;
}
__device__ __forceinline__ u16 f2b(float f){
  union { float f; u32 i; } x; x.f = f;
  u32 r = x.i + 0x7fffu + ((x.i >> 16) & 1u);   // RNE
  return (u16)(r >> 16);
}
// v_rcp_f32 (~1 ulp) instead of precise-division sequence: bf16-negligible error.
__device__ __forceinline__ float rcp_(float x){ return __builtin_amdgcn_rcpf(x); }
__device__ __forceinline__ float sigm(float x){ return rcp_(1.f + __expf(-x)); }
__device__ __forceinline__ float tanh_(float x){
  x = fminf(fmaxf(x, -15.f), 15.f);
  float e = __expf(2.f*x);
  return (e - 1.f) * rcp_(e + 1.f);
}
__device__ __forceinline__ int swz(int r){ return (r + (r >> 2)) & 3; }
// LDS sum-tile swizzle: [32][256] u16, 16B-chunk index XORed with row&7.
__device__ __forceinline__ int lds_off(int row, int col){
  return row*256 + ((((col >> 3) ^ (row & 7)) << 3) + (col & 7));
}
// ILV u16 index within a hE row for h / E element at col j.
__device__ __forceinline__ int ilv_h(int j){ return (j>>2)*8 + (j&3); }
__device__ __forceinline__ int ilv_e(int j){ return (j>>2)*8 + 4 + (j&3); }

// ---- Per-vocab tables, f32-exact. Grid (V, 4): block = (vocab v, matrix q).
// q==1 stores tXr = exp(-(x@Wr.T + bu))  (gather consumes the exponential form).
__global__ void k_tables(const float* __restrict__ emb,
    const float* __restrict__ Wz, const float* __restrict__ bz,
    const float* __restrict__ Wr, const float* __restrict__ bu,
    const float* __restrict__ Wh, const float* __restrict__ bh,
    const float* __restrict__ Wo, const float* __restrict__ bo,
    float* __restrict__ tWz, float* __restrict__ tXr,
    float* __restrict__ tWh, float* __restrict__ tWo){
  int v = blockIdx.x, q = blockIdx.y, j = threadIdx.x;
  __shared__ float e[H_];
  e[j] = emb[v*H_ + j];
  __syncthreads();
  const float* w; const float* b; float* o; int ld;
  if      (q == 0){ w = Wz; b = bz; o = tWz; ld = 2*H_; }
  else if (q == 1){ w = Wr; b = bu; o = tXr; ld = H_;   }
  else if (q == 2){ w = Wh; b = bh; o = tWh; ld = 2*H_; }
  else            { w = Wo; b = bo; o = tWo; ld = 2*H_; }
  const float* wr = w + (size_t)j*ld;
  float a0 = 0.f, a1 = 0.f;
  #pragma unroll 4
  for (int i = 0; i < H_; i += 8){
    float4 x = *(const float4*)(wr + i);
    float4 y = *(const float4*)(wr + i + 4);
    a0 += e[i  ]*x.x + e[i+1]*x.y + e[i+2]*x.z + e[i+3]*x.w;
    a1 += e[i+4]*y.x + e[i+5]*y.y + e[i+6]*y.z + e[i+7]*y.w;
  }
  float val = a0 + a1 + b[j];
  if (q == 1) val = __expf(-val);
  o[v*H_ + j] = val;
}

// ---- Convert the three K-major 256x256 weight slices to bf16.
__global__ void k_convw(const float* __restrict__ Ur, const float* __restrict__ Wz,
                        const float* __restrict__ Wh,
                        u16* __restrict__ Urb, u16* __restrict__ Wzb, u16* __restrict__ Whb){
  int r = blockIdx.x, j = threadIdx.x;
  Urb[r*H_ + j] = f2b(Ur[r*H_ + j]);
  Wzb[r*H_ + j] = f2b(Wz[r*(2*H_) + H_ + j]);   // columns H..2H of Wz row r
  Whb[r*H_ + j] = f2b(Wh[r*(2*H_) + H_ + j]);
}

// ---- vmsg[m] = fnode[fmess[m]]; h1 closed form (h0=0), bf16, masked at m==0.
// Writes h into the ILV hE row AND into the plain hA buffer (k_gemm's A input).
__global__ void k_init(const int* __restrict__ fnode, const int* __restrict__ fmess,
                       const float* __restrict__ tWz, const float* __restrict__ tWh,
                       int* __restrict__ vmsg, u16* __restrict__ hE,
                       u16* __restrict__ hA){
  int m = blockIdx.x, j = threadIdx.x;
  int v = fnode[fmess[m]];
  if (j == 0) vmsg[m] = v;
  float val = (m == 0) ? 0.f : sigm(tWz[v*H_ + j])*tanh_(tWh[v*H_ + j]);
  u16 b = f2b(val);
  hE[(size_t)m*HE_LD + ilv_h(j)] = b;
  hA[(size_t)m*H_ + j] = b;
}

// ---- Initial E slots of hE = exp(-(h @ Ur.T)). Runs ONCE (after k_init).
// A = plain hA (stride 256). 256 threads, BM=64, BN=256, BK=32, dbuf pipeline.
__global__ __launch_bounds__(256,3) void k_gemm(
    const u16* __restrict__ A, const u16* __restrict__ W, u16* __restrict__ C){
  __shared__ __align__(16) u16 lA[2][64*32];
  __shared__ __align__(16) u16 lB[2][256*32];
  const int t    = threadIdx.x;
  const int m0   = blockIdx.x * 64;
  const int lane = t & 63, wave = t >> 6;     // 4 waves: 1 row x 4 col tiles
  const int l16  = lane & 15, kc8 = lane >> 4;

  const int rA = t >> 2, cA = t & 3;
  const int kA = (cA ^ swz(rA)) * 8;
  const int gmA = (m0 + rA < M_) ? (m0 + rA) : (M_ - 1);
  const int aOff = (wave*64)*8;               // wave-uniform LDS base (u16 units)
  int rB[4], kB[4], bOff[4];
  #pragma unroll
  for (int p=0;p<4;p++){
    int s = t + 256*p;
    rB[p] = s >> 2; int cc = s & 3;
    kB[p] = (cc ^ swz(rB[p])) * 8;
    bOff[p] = (wave*64 + 256*p)*8;
  }

  f32x4 acc[4][4];
  #pragma unroll
  for (int r=0;r<4;r++)
    #pragma unroll
    for (int c=0;c<4;c++)
      #pragma unroll
      for (int q=0;q<4;q++) acc[r][c][q] = 0.f;

  auto stage = [&](int buf, int k0){
    dma16(A + (size_t)gmA*H_ + k0 + kA, &lA[buf][aOff]);
    #pragma unroll
    for (int p=0;p<4;p++)
      dma16(W + (size_t)rB[p]*H_ + k0 + kB[p], &lB[buf][bOff[p]]);
  };

  stage(0, 0);
  __syncthreads();                            // buf0 DMA complete
  int cur = 0;
  for (int ks = 0; ks < 8; ++ks){
    if (ks < 7) stage(cur^1, (ks+1)*32);      // prefetch next tile (overlaps compute)
    bf16x8 aF[4], bF[4];
    #pragma unroll
    for (int r=0;r<4;r++){
      int row = r*16 + l16;
      aF[r] = *(const bf16x8*)(&lA[cur][row*32 + ((kc8 ^ swz(row))*8)]);
    }
    #pragma unroll
    for (int c=0;c<4;c++){
      int row = wave*64 + c*16 + l16;
      bF[c] = *(const bf16x8*)(&lB[cur][row*32 + ((kc8 ^ swz(row))*8)]);
    }
    #pragma unroll
    for (int r=0;r<4;r++)
      #pragma unroll
      for (int c=0;c<4;c++)
        acc[r][c] = __builtin_amdgcn_mfma_f32_16x16x32_bf16(aF[r], bF[c], acc[r][c], 0,0,0);
    if (ks < 7) __syncthreads();              // drains DMA; protects buffer reuse
    cur ^= 1;
  }

  #pragma unroll
  for (int r=0;r<4;r++){
    #pragma unroll
    for (int c=0;c<4;c++){
      int mb = m0 + r*16 + kc8*4;             // C/D: row=(lane>>4)*4+reg
      int n  = wave*64 + c*16 + l16;          //      col=lane&15
      #pragma unroll
      for (int q=0;q<4;q++){
        int m = mb + q;
        if (m < M_) C[(size_t)m*HE_LD + ilv_e(n)] = f2b(__expf(-acc[r][c][q]));
      }
    }
  }
}

// ---- FUSED iteration step: gather -> dual GEMM -> GRU -> Ur GEMM -> E.
// 512 threads (8 waves), BM=32, BN=256, 32KB LDS, launch_bounds(512,8)
// -> 4 blocks/CU = 32 waves (100% occupancy) for the latency-bound gather.
// ALL bulk writes staged through LDS and emitted as full-row (1 KB/wave)
// streaming stores: R5's scattered 2B stores caused 3.3x write amplification
// (WRITE 340MB vs 102 logical) + ~200MB RFO fetches. Ping-pong src/dst.
template<bool FIN>
__global__ __launch_bounds__(512,8) void k_step(
    const u16* __restrict__ src, u16* __restrict__ dst,
    float* __restrict__ hf,
    const int* __restrict__ mg, const int* __restrict__ vmsg,
    const float* __restrict__ tXr, const float* __restrict__ tWz,
    const float* __restrict__ tWh,
    const u16* __restrict__ Wzb, const u16* __restrict__ Whb,
    const u16* __restrict__ Urb){
  __shared__ __align__(16) u16 lds_[2*32*256];   // 32 KB arena
  u16* lSH = lds_;             // sum_h; later E (non-FIN) / f32 rows (FIN)
  u16* lSG = lds_ + 32*256;    // sum_gated; later h_new
  const int t    = threadIdx.x;
  const int m0   = blockIdx.x * 32;
  const int lane = t & 63, wave = t >> 6;
  const int l16  = lane & 15, kc8 = lane >> 4;
  const int wrow = wave >> 2, wcol = wave & 3;   // 2 x 4 -> wave-tile 16x64

  // ---- P1: neighbor gather, sums -> LDS. Wave w owns local rows w*4..w*4+3.
  {
    const char* bc = (const char*)src;
    const u32 cb = (u32)lane * 16u;
    for (int i = 0; i < 4; ++i){
      int row = wave*4 + i;                    // local row
      int gm = m0 + row; if (gm >= M_) gm = M_ - 1;
      int v = vmsg[gm];
      float4 X = *(const float4*)(tXr + (size_t)v*H_ + lane*4);
      const int2* mgp = (const int2*)(mg + gm*K_);   // 24B stride -> 8-aligned
      int2 g01 = mgp[0], g23 = mgp[1], g45 = mgp[2];
      int gs[K_] = {g01.x,g01.y,g23.x,g23.y,g45.x,g45.y};
      float s0=0.f,s1=0.f,s2=0.f,s3=0.f, a0=0.f,a1=0.f,a2=0.f,a3=0.f;
      #pragma unroll
      for (int k=0;k<K_;k++){
        u32 off = ((u32)gs[k] << 10) + cb;
        uint4 p = *(const uint4*)(bc + off);   // [h 4l..4l+3 | E 4l..4l+3]
        float h0=b2f((u16)p.x), h1=b2f((u16)(p.x>>16));
        float h2=b2f((u16)p.y), h3=b2f((u16)(p.y>>16));
        float e0=b2f((u16)p.z), e1=b2f((u16)(p.z>>16));
        float e2=b2f((u16)p.w), e3=b2f((u16)(p.w>>16));
        s0+=h0; s1+=h1; s2+=h2; s3+=h3;
        a0 += rcp_(fmaf(X.x,e0,1.f))*h0;
        a1 += rcp_(fmaf(X.y,e1,1.f))*h1;
        a2 += rcp_(fmaf(X.z,e2,1.f))*h2;
        a3 += rcp_(fmaf(X.w,e3,1.f))*h3;
      }
      uint2 sh, sg;
      sh.x = (u32)f2b(s0) | ((u32)f2b(s1)<<16);
      sh.y = (u32)f2b(s2) | ((u32)f2b(s3)<<16);
      sg.x = (u32)f2b(a0) | ((u32)f2b(a1)<<16);
      sg.y = (u32)f2b(a2) | ((u32)f2b(a3)<<16);
      int o = lds_off(row, lane*4);
      *(uint2*)&lSH[o] = sh;
      *(uint2*)&lSG[o] = sg;
    }
  }
  __syncthreads();

  // ---- P2: dual GEMM (z and pre-h), A from LDS, B direct from global (L2-hot).
  f32x4 accZ[4], accH[4];
  #pragma unroll
  for (int c=0;c<4;c++)
    #pragma unroll
    for (int q=0;q<4;q++){ accZ[c][q]=0.f; accH[c][q]=0.f; }

  #pragma unroll
  for (int ks=0; ks<8; ++ks){
    int arow = wrow*16 + l16;
    int ao = arow*256 + ((((ks*4 + kc8) ^ (arow & 7)) << 3));
    bf16x8 aH = *(const bf16x8*)&lSH[ao];
    bf16x8 aG = *(const bf16x8*)&lSG[ao];
    #pragma unroll
    for (int c=0;c<4;c++){
      int n = wcol*64 + c*16 + l16;
      bf16x8 bZ = *(const bf16x8*)(Wzb + (size_t)n*H_ + ks*32 + kc8*8);
      bf16x8 bW = *(const bf16x8*)(Whb + (size_t)n*H_ + ks*32 + kc8*8);
      accZ[c] = __builtin_amdgcn_mfma_f32_16x16x32_bf16(aH, bZ, accZ[c], 0,0,0);
      accH[c] = __builtin_amdgcn_mfma_f32_16x16x32_bf16(aG, bW, accH[c], 0,0,0);
    }
  }
  __syncthreads();   // all P2 LDS reads complete before h_new overwrites lSG

  // ---- P3: GRU epilogue. sumh from LDS.
  // non-FIN: h_new -> lSG (bf16). FIN: stash f32 o in accZ (regs).
  #pragma unroll
  for (int q=0;q<4;q++){
    int lm = wrow*16 + kc8*4 + q;             // local row (C/D: row=(lane>>4)*4+q)
    int m  = m0 + lm;
    int v  = (m < M_) ? vmsg[m] : 0;
    #pragma unroll
    for (int c=0;c<4;c++){
      int n = wcol*64 + c*16 + l16;
      float z   = sigm(tWz[v*H_ + n] + accZ[c][q]);
      float pre = tanh_(tWh[v*H_ + n] + accH[c][q]);
      float sh  = b2f(lSH[lds_off(lm, n)]);
      float o   = (m == 0) ? 0.f : (1.f - z)*sh + z*pre;
      if (FIN) accZ[c][q] = o;                // keep f32 exact for final write
      else     lSG[lds_off(lm, n)] = f2b(o);  // h_new tile (sumg arena reused)
    }
  }

  if (FIN){
    __syncthreads();                          // all lSH (sh) reads done
    // f32 tile [32][256] over the whole 32 KB arena, chunk-swizzled.
    float* lF = (float*)lds_;
    #pragma unroll
    for (int q=0;q<4;q++){
      int lm = wrow*16 + kc8*4 + q;
      #pragma unroll
      for (int c=0;c<4;c++){
        int n = wcol*64 + c*16 + l16;
        int cs = (n>>2) ^ ((lm & 7) << 3);
        lF[lm*256 + (cs<<2) + (n&3)] = accZ[c][q];
      }
    }
    __syncthreads();
    // Cooperative full-row write: one wave writes one 1 KB f32 row.
    for (int i=0;i<4;i++){
      int row = wave*4 + i;
      int m = m0 + row;
      if (m >= M_) continue;
      float4 vv = *(const float4*)&lF[row*256 + (((lane ^ ((row&7)<<3)))<<2)];
      *(float4*)(hf + (size_t)m*H_ + lane*4) = vv;
    }
    return;
  }

  __syncthreads();   // h_new complete before P4 A-fragment reads

  // ---- P4: E = exp(-(h_new @ Ur.T)), A from LDS h_new, B direct from global.
  f32x4 accE[4];
  #pragma unroll
  for (int c=0;c<4;c++)
    #pragma unroll
    for (int q=0;q<4;q++) accE[c][q] = 0.f;

  #pragma unroll
  for (int ks=0; ks<8; ++ks){
    int arow = wrow*16 + l16;
    int ao = arow*256 + ((((ks*4 + kc8) ^ (arow & 7)) << 3));
    bf16x8 aN = *(const bf16x8*)&lSG[ao];
    #pragma unroll
    for (int c=0;c<4;c++){
      int n = wcol*64 + c*16 + l16;
      bf16x8 bU = *(const bf16x8*)(Urb + (size_t)n*H_ + ks*32 + kc8*8);
      accE[c] = __builtin_amdgcn_mfma_f32_16x16x32_bf16(aN, bU, accE[c], 0,0,0);
    }
  }
  // E -> lSH (sum_h arena is dead after P3).
  #pragma unroll
  for (int q=0;q<4;q++){
    int lm = wrow*16 + kc8*4 + q;
    #pragma unroll
    for (int c=0;c<4;c++){
      int n = wcol*64 + c*16 + l16;
      lSH[lds_off(lm, n)] = f2b(__expf(-accE[c][q]));
    }
  }
  __syncthreads();

  // ---- P5: cooperative full-row ILV write: one wave writes one 1 KB row.
  // dst chunk l (16 B) = [h(4l..4l+3) from lSG | E(4l..4l+3) from lSH].
  {
    const int c2 = lane >> 1, c1 = (lane & 1) * 4;
    for (int i=0;i<4;i++){
      int row = wave*4 + i;
      int m = m0 + row;
      if (m >= M_) continue;
      int xr = row & 7;
      int lo = row*256 + (((c2 ^ xr) << 3)) + c1;
      uint2 hh = *(const uint2*)&lSG[lo];
      uint2 ee = *(const uint2*)&lSH[lo];
      uint4 w; w.x = hh.x; w.y = hh.y; w.z = ee.x; w.w = ee.y;
      *(uint4*)((char*)dst + ((size_t)m << 10) + lane*16) = w;
    }
  }
}

// ---- Readout: only B=64 scope rows are needed. h f32 (final), out f32.
__global__ void k_final(const float* __restrict__ h, const int* __restrict__ ng,
                        const int* __restrict__ fnode, const int* __restrict__ scope,
                        const float* __restrict__ tWo, const float* __restrict__ Wo,
                        float* __restrict__ out){
  int b = blockIdx.x, j = threadIdx.x;
  int n = scope[b];
  __shared__ float mn[H_];
  float s = 0.f;
  #pragma unroll
  for (int k=0;k<K_;k++){
    int g = ng[n*K_ + k];
    s += h[(size_t)g*H_ + j];
  }
  mn[j] = s;
  __syncthreads();
  int v = fnode[n];
  float acc = tWo[v*H_ + j];
  const float* w = Wo + j*(2*H_) + H_;
  for (int i=0;i<H_;i+=4){
    float4 a = *(const float4*)(w+i);
    acc += mn[i]*a.x + mn[i+1]*a.y + mn[i+2]*a.z + mn[i+3]*a.w;
  }
  out[b*H_ + j] = fmaxf(acc, 0.f);
}

// ---- Guard signal: all-zero f32 output.
__global__ void k_zero(float* __restrict__ out, int n){
  int i = blockIdx.x*256 + threadIdx.x;
  int stride = gridDim.x*256;
  for (; i < n; i += stride) out[i] = 0.f;
}

extern "C" void kernel_launch(void* const* d_in, const int* in_sizes, int n_in,
                              void* d_out, int out_size, void* d_ws, size_t ws_size,
                              hipStream_t stream){
  const int* fnode      = (const int*)d_in[0];
  const int* fmess      = (const int*)d_in[1];
  const int* node_graph = (const int*)d_in[2];
  const int* mess_graph = (const int*)d_in[3];
  const int* scope_st   = (const int*)d_in[4];
  const float* emb = (const float*)d_in[5];
  const float* Wz  = (const float*)d_in[6];
  const float* bz  = (const float*)d_in[7];
  const float* Wr  = (const float*)d_in[8];
  const float* Ur  = (const float*)d_in[9];
  const float* bu  = (const float*)d_in[10];
  const float* Wh  = (const float*)d_in[11];
  const float* bh  = (const float*)d_in[12];
  const float* Wo  = (const float*)d_in[13];
  const float* bo  = (const float*)d_in[14];

  char* ws = (char*)d_ws;
  size_t off = 0;
  float* tWz = (float*)(ws + off); off += (size_t)V_*H_*4;
  float* tXr = (float*)(ws + off); off += (size_t)V_*H_*4;
  float* tWh = (float*)(ws + off); off += (size_t)V_*H_*4;
  float* tWo = (float*)(ws + off); off += (size_t)V_*H_*4;
  u16* Urb  = (u16*)(ws + off); off += (size_t)H_*H_*2;
  u16* Wzb  = (u16*)(ws + off); off += (size_t)H_*H_*2;
  u16* Whb  = (u16*)(ws + off); off += (size_t)H_*H_*2;
  int* vmsg = (int*)(ws + off); off += ((size_t)M_*4 + 1023) & ~(size_t)1023;
  u16* hA   = (u16*)(ws + off); off += (size_t)M_*H_*2;      // plain h (k_gemm A)
  u16* hEws = (u16*)(ws + off); off += (size_t)M_*HE_LD*2;   // ping buffer

  if (ws_size < off){
    k_zero<<<2048, 256, 0, stream>>>((float*)d_out, out_size);
    return;
  }

  float* out = (float*)d_out;          // output dtype f32 (established R6)
  float* h   = out + (size_t)B_*H_;    // h (output 1) lives in d_out, f32
  // d_out's f32 h region (M*256*4 B) doubles as the pong hE buffer
  // (M*512*2 B -- exact same size). Final k_step overwrites it with f32 h.
  u16* hED = (u16*)h;

  const int MT64 = (M_ + 63)/64;       // 1563 row tiles (BM=64, k_gemm)
  const int MT32 = (M_ + 31)/32;       // 3126 row tiles (BM=32, k_step)

  k_tables<<<dim3(V_,4), H_, 0, stream>>>(emb, Wz, bz, Wr, bu, Wh, bh, Wo, bo,
                                          tWz, tXr, tWh, tWo);
  k_convw<<<H_, H_, 0, stream>>>(Ur, Wz, Wh, Urb, Wzb, Whb);
  k_init<<<M_, H_, 0, stream>>>(fnode, fmess, tWz, tWh, vmsg, hEws, hA);
  k_gemm<<<MT64, 256, 0, stream>>>(hA, Urb, hEws);   // E1 (once)

  // Ping-pong: ws -> D -> ws -> D -> ws; final step reads ws, writes f32 h (D).
  k_step<false><<<MT32, 512, 0, stream>>>(hEws, hED,  h, mess_graph, vmsg,
                                          tXr, tWz, tWh, Wzb, Whb, Urb);
  k_step<false><<<MT32, 512, 0, stream>>>(hED,  hEws, h, mess_graph, vmsg,
                                          tXr, tWz, tWh, Wzb, Whb, Urb);
  k_step<false><<<MT32, 512, 0, stream>>>(hEws, hED,  h, mess_graph, vmsg,
                                          tXr, tWz, tWh, Wzb, Whb, Urb);
  k_step<false><<<MT32, 512, 0, stream>>>(hED,  hEws, h, mess_graph, vmsg,
                                          tXr, tWz, tWh, Wzb, Whb, Urb);
  k_step<true ><<<MT32, 512, 0, stream>>>(hEws, hEws, h, mess_graph, vmsg,
                                          tXr, tWz, tWh, Wzb, Whb, Urb);

  k_final<<<B_, H_, 0, stream>>>(h, node_graph, fnode, scope_st, tWo, Wo, out);
}

// Round 7
// 2010.948 us; speedup vs baseline: 1.1649x; 1.1649x over previous
//
#include <hip/hip_runtime.h>

typedef unsigned short u16;
typedef unsigned int   u32;
typedef short bf16x8 __attribute__((ext_vector_type(8)));
typedef float f32x4  __attribute__((ext_vector_type(4)));

#define V_ 780
#define N_ 50000
#define M_ 100001
#define K_ 6
#define H_ 256
#define B_ 64
#define DEPTH_ 6

// hE packed row: 512 u16 = 64 chunks of 16 B; chunk c = [h(4c..4c+3)|E(4c..4c+3)].
// Cols 0..127 live in bytes 0..511 of the row; cols 128..255 in bytes 512..1023
// -> the column-split gather touches disjoint 512 B halves per pass.
#define HE_LD 512

typedef __attribute__((address_space(3))) u32 lds_u32;
typedef __attribute__((address_space(1))) const u32 glb_u32;
__device__ __forceinline__ void dma16(const void* g, void* l){
  __builtin_amdgcn_global_load_lds((glb_u32*)g, (lds_u32*)l, 16, 0, 0);
}

__device__ __forceinline__ float b2f(u16 u){
  union { u32 i; float f; } x; x.i = ((u32)u) << 16; return x.f;
}
__device__ __forceinline__ u16 f2b(float f){
  union { float f; u32 i; } x; x.f = f;
  u32 r = x.i + 0x7fffu + ((x.i >> 16) & 1u);   // RNE
  return (u16)(r >> 16);
}
// v_rcp_f32 (~1 ulp) instead of precise-division sequence: bf16-negligible error.
__device__ __forceinline__ float rcp_(float x){ return __builtin_amdgcn_rcpf(x); }
__device__ __forceinline__ float sigm(float x){ return rcp_(1.f + __expf(-x)); }
__device__ __forceinline__ float tanh_(float x){
  x = fminf(fmaxf(x, -15.f), 15.f);
  float e = __expf(2.f*x);
  return (e - 1.f) * rcp_(e + 1.f);
}
__device__ __forceinline__ int swz(int r){ return (r + (r >> 2)) & 3; }
// LDS tile swizzle for [64][256] u16: 16B-chunk index XORed with row&7.
__device__ __forceinline__ int lds_off64(int row, int col){
  return row*256 + ((((col >> 3) ^ (row & 7)) << 3) + (col & 7));
}
// ILV u16 index within a hE row for h / E element at col j.
__device__ __forceinline__ int ilv_h(int j){ return (j>>2)*8 + (j&3); }
__device__ __forceinline__ int ilv_e(int j){ return (j>>2)*8 + 4 + (j&3); }

// ---- Per-vocab tables, f32-exact. Grid (V, 4): block = (vocab v, matrix q).
// q==1 stores tXr = exp(-(x@Wr.T + bu))  (gather consumes the exponential form).
__global__ void k_tables(const float* __restrict__ emb,
    const float* __restrict__ Wz, const float* __restrict__ bz,
    const float* __restrict__ Wr, const float* __restrict__ bu,
    const float* __restrict__ Wh, const float* __restrict__ bh,
    const float* __restrict__ Wo, const float* __restrict__ bo,
    float* __restrict__ tWz, float* __restrict__ tXr,
    float* __restrict__ tWh, float* __restrict__ tWo){
  int v = blockIdx.x, q = blockIdx.y, j = threadIdx.x;
  __shared__ float e[H_];
  e[j] = emb[v*H_ + j];
  __syncthreads();
  const float* w; const float* b; float* o; int ld;
  if      (q == 0){ w = Wz; b = bz; o = tWz; ld = 2*H_; }
  else if (q == 1){ w = Wr; b = bu; o = tXr; ld = H_;   }
  else if (q == 2){ w = Wh; b = bh; o = tWh; ld = 2*H_; }
  else            { w = Wo; b = bo; o = tWo; ld = 2*H_; }
  const float* wr = w + (size_t)j*ld;
  float a0 = 0.f, a1 = 0.f;
  #pragma unroll 4
  for (int i = 0; i < H_; i += 8){
    float4 x = *(const float4*)(wr + i);
    float4 y = *(const float4*)(wr + i + 4);
    a0 += e[i  ]*x.x + e[i+1]*x.y + e[i+2]*x.z + e[i+3]*x.w;
    a1 += e[i+4]*y.x + e[i+5]*y.y + e[i+6]*y.z + e[i+7]*y.w;
  }
  float val = a0 + a1 + b[j];
  if (q == 1) val = __expf(-val);
  o[v*H_ + j] = val;
}

// ---- Convert the three K-major 256x256 weight slices to bf16.
__global__ void k_convw(const float* __restrict__ Ur, const float* __restrict__ Wz,
                        const float* __restrict__ Wh,
                        u16* __restrict__ Urb, u16* __restrict__ Wzb, u16* __restrict__ Whb){
  int r = blockIdx.x, j = threadIdx.x;
  Urb[r*H_ + j] = f2b(Ur[r*H_ + j]);
  Wzb[r*H_ + j] = f2b(Wz[r*(2*H_) + H_ + j]);   // columns H..2H of Wz row r
  Whb[r*H_ + j] = f2b(Wh[r*(2*H_) + H_ + j]);
}

// ---- vmsg[m] = fnode[fmess[m]]; h1 closed form (h0=0), bf16, masked at m==0.
// Writes h into the ILV hE row AND into the plain hA buffer (k_gemm's A input).
__global__ void k_init(const int* __restrict__ fnode, const int* __restrict__ fmess,
                       const float* __restrict__ tWz, const float* __restrict__ tWh,
                       int* __restrict__ vmsg, u16* __restrict__ hE,
                       u16* __restrict__ hA){
  int m = blockIdx.x, j = threadIdx.x;
  int v = fnode[fmess[m]];
  if (j == 0) vmsg[m] = v;
  float val = (m == 0) ? 0.f : sigm(tWz[v*H_ + j])*tanh_(tWh[v*H_ + j]);
  u16 b = f2b(val);
  hE[(size_t)m*HE_LD + ilv_h(j)] = b;
  hA[(size_t)m*H_ + j] = b;
}

// ---- Initial E slots of hE = exp(-(h1 @ Ur.T)). Runs ONCE (after k_init).
// A = plain hA (stride 256). 256 threads, BM=64, BN=256, BK=32, dbuf pipeline.
__global__ __launch_bounds__(256,3) void k_gemm(
    const u16* __restrict__ A, const u16* __restrict__ W, u16* __restrict__ C){
  __shared__ __align__(16) u16 lA[2][64*32];
  __shared__ __align__(16) u16 lB[2][256*32];
  const int t    = threadIdx.x;
  const int m0   = blockIdx.x * 64;
  const int lane = t & 63, wave = t >> 6;     // 4 waves: 1 row x 4 col tiles
  const int l16  = lane & 15, kc8 = lane >> 4;

  const int rA = t >> 2, cA = t & 3;
  const int kA = (cA ^ swz(rA)) * 8;
  const int gmA = (m0 + rA < M_) ? (m0 + rA) : (M_ - 1);
  const int aOff = (wave*64)*8;               // wave-uniform LDS base (u16 units)
  int rB[4], kB[4], bOff[4];
  #pragma unroll
  for (int p=0;p<4;p++){
    int s = t + 256*p;
    rB[p] = s >> 2; int cc = s & 3;
    kB[p] = (cc ^ swz(rB[p])) * 8;
    bOff[p] = (wave*64 + 256*p)*8;
  }

  f32x4 acc[4][4];
  #pragma unroll
  for (int r=0;r<4;r++)
    #pragma unroll
    for (int c=0;c<4;c++)
      #pragma unroll
      for (int q=0;q<4;q++) acc[r][c][q] = 0.f;

  auto stage = [&](int buf, int k0){
    dma16(A + (size_t)gmA*H_ + k0 + kA, &lA[buf][aOff]);
    #pragma unroll
    for (int p=0;p<4;p++)
      dma16(W + (size_t)rB[p]*H_ + k0 + kB[p], &lB[buf][bOff[p]]);
  };

  stage(0, 0);
  __syncthreads();                            // buf0 DMA complete
  int cur = 0;
  for (int ks = 0; ks < 8; ++ks){
    if (ks < 7) stage(cur^1, (ks+1)*32);      // prefetch next tile (overlaps compute)
    bf16x8 aF[4], bF[4];
    #pragma unroll
    for (int r=0;r<4;r++){
      int row = r*16 + l16;
      aF[r] = *(const bf16x8*)(&lA[cur][row*32 + ((kc8 ^ swz(row))*8)]);
    }
    #pragma unroll
    for (int c=0;c<4;c++){
      int row = wave*64 + c*16 + l16;
      bF[c] = *(const bf16x8*)(&lB[cur][row*32 + ((kc8 ^ swz(row))*8)]);
    }
    #pragma unroll
    for (int r=0;r<4;r++)
      #pragma unroll
      for (int c=0;c<4;c++)
        acc[r][c] = __builtin_amdgcn_mfma_f32_16x16x32_bf16(aF[r], bF[c], acc[r][c], 0,0,0);
    if (ks < 7) __syncthreads();              // drains DMA; protects buffer reuse
    cur ^= 1;
  }

  #pragma unroll
  for (int r=0;r<4;r++){
    #pragma unroll
    for (int c=0;c<4;c++){
      int mb = m0 + r*16 + kc8*4;             // C/D: row=(lane>>4)*4+reg
      int n  = wave*64 + c*16 + l16;          //      col=lane&15
      #pragma unroll
      for (int q=0;q<4;q++){
        int m = mb + q;
        if (m < M_) C[(size_t)m*HE_LD + ilv_e(n)] = f2b(__expf(-acc[r][c][q]));
      }
    }
  }
}

// ---- Column-split neighbor gather: pass p covers cols p*128..p*128+127.
// Barrier-free, ~28 VGPR, full occupancy. Per-pass random working set = 51 MB
// of hE row-halves -> L3-resident, so the ~6x re-reads become L3 hits.
// Lanes 0-31 handle msg A, lanes 32-63 msg B (2 msgs/wave, 8 msgs/block).
// sigm(xr+u) = rcp(fma(X, E, 1)): X = tXr (f32), E = exp(-hUr) (bf16).
__global__ __launch_bounds__(256,8) void k_gather2(
    const u16* __restrict__ hE,
    const int* __restrict__ mg, const int* __restrict__ vmsg,
    const float* __restrict__ tXr,
    u16* __restrict__ sumh, u16* __restrict__ sumg, int pass){
  int m = blockIdx.x*8 + ((threadIdx.x>>6)<<1) + ((threadIdx.x>>5)&1);
  if (m >= M_) return;
  const int hl = threadIdx.x & 31;            // column-chunk index within half
  int v = vmsg[m];
  float4 X = *(const float4*)(tXr + (size_t)v*H_ + pass*128 + hl*4);
  const int2* mgp = (const int2*)(mg + m*K_);  // 24B stride -> 8-aligned
  int2 g01 = mgp[0], g23 = mgp[1], g45 = mgp[2];
  int gs[K_] = {g01.x,g01.y,g23.x,g23.y,g45.x,g45.y};
  const char* bc = (const char*)hE;
  const u32 cb = (u32)(pass*512 + hl*16);
  float s0=0.f,s1=0.f,s2=0.f,s3=0.f, a0=0.f,a1=0.f,a2=0.f,a3=0.f;
  #pragma unroll
  for (int k=0;k<K_;k++){
    u32 off = ((u32)gs[k] << 10) + cb;        // 32-bit byte offset (<103 MB)
    uint4 p = *(const uint4*)(bc + off);      // [h 4hl..4hl+3 | E 4hl..4hl+3]
    float h0=b2f((u16)p.x), h1=b2f((u16)(p.x>>16));
    float h2=b2f((u16)p.y), h3=b2f((u16)(p.y>>16));
    float e0=b2f((u16)p.z), e1=b2f((u16)(p.z>>16));
    float e2=b2f((u16)p.w), e3=b2f((u16)(p.w>>16));
    s0+=h0; s1+=h1; s2+=h2; s3+=h3;
    a0 += rcp_(fmaf(X.x,e0,1.f))*h0;
    a1 += rcp_(fmaf(X.y,e1,1.f))*h1;
    a2 += rcp_(fmaf(X.z,e2,1.f))*h2;
    a3 += rcp_(fmaf(X.w,e3,1.f))*h3;
  }
  uint2 sh, sg;
  sh.x = (u32)f2b(s0) | ((u32)f2b(s1)<<16);
  sh.y = (u32)f2b(s2) | ((u32)f2b(s3)<<16);
  sg.x = (u32)f2b(a0) | ((u32)f2b(a1)<<16);
  sg.y = (u32)f2b(a2) | ((u32)f2b(a3)<<16);
  *(uint2*)((char*)sumh + ((size_t)m<<9) + pass*256 + hl*8) = sh;
  *(uint2*)((char*)sumg + ((size_t)m<<9) + pass*256 + hl*8) = sg;
}

// ---- MERGED: dual GEMM (z,pre-h) + GRU epilogue + E = exp(-(h_new @ Ur.T)).
// 512 threads (8 waves = 2x4), BM=64, BN=256. sumh/sumg DMA-dbuf staged
// (16 KB); Wzb/Whb/Urb direct from L2-hot global; h_new tile in LDS (32 KB)
// feeds the E-GEMM. 48 KB LDS, ~2 blk/CU (scattered stores safe at this
// concurrency per R0-R3). FIN: write f32 h, skip E-GEMM.
template<bool FIN>
__global__ __launch_bounds__(512,2) void k_gemmzh_e(
    const u16* __restrict__ sumh, const u16* __restrict__ sumg,
    const u16* __restrict__ Wzb, const u16* __restrict__ Whb,
    const u16* __restrict__ Urb,
    const float* __restrict__ tWz, const float* __restrict__ tWh,
    const int* __restrict__ vmsg,
    u16* __restrict__ dst, float* __restrict__ hf){
  __shared__ __align__(16) u16 lA[2][2][64*32];   // [buf][sumh|sumg]
  __shared__ __align__(16) u16 lN[64*256];        // h_new arena
  const int t    = threadIdx.x;
  const int m0   = blockIdx.x * 64;
  const int lane = t & 63, wave = t >> 6;
  const int l16  = lane & 15, kc8 = lane >> 4;
  const int wrow = wave >> 2, wcol = wave & 3;    // wave-tile 32x64

  // Staging: 512 slots/step (2 mats x 64 rows x 4 chunks), 1 slot/thread.
  const int mat = t >> 8;                         // waves 0-3: sumh, 4-7: sumg
  const int tm  = t & 255;
  const int rS  = tm >> 2, cS = tm & 3;
  const int kS  = (cS ^ swz(rS)) * 8;
  const int gmS = (m0 + rS < M_) ? (m0 + rS) : (M_ - 1);
  const u16* matp = mat ? sumg : sumh;
  const int dOff = ((wave & 3) * 64) * 8;         // wave-uniform LDS base

  f32x4 accZ[2][4], accH[2][4];
  #pragma unroll
  for (int r=0;r<2;r++)
    #pragma unroll
    for (int c=0;c<4;c++)
      #pragma unroll
      for (int q=0;q<4;q++){ accZ[r][c][q]=0.f; accH[r][c][q]=0.f; }

  auto stage = [&](int buf, int k0){
    dma16(matp + (size_t)gmS*H_ + k0 + kS, &lA[buf][mat][dOff]);
  };

  stage(0, 0);
  __syncthreads();
  int cur = 0;
  for (int ks = 0; ks < 8; ++ks){
    bf16x8 aH[2], aG[2];
    #pragma unroll
    for (int r=0;r<2;r++){
      int row = wrow*32 + r*16 + l16;
      int ao = row*32 + ((kc8 ^ swz(row))*8);
      aH[r] = *(const bf16x8*)&lA[cur][0][ao];
      aG[r] = *(const bf16x8*)&lA[cur][1][ao];
    }
    if (ks < 7) stage(cur^1, (ks+1)*32);          // overlaps this step's MFMAs
    #pragma unroll
    for (int c=0;c<4;c++){
      int n = wcol*64 + c*16 + l16;
      bf16x8 bZ = *(const bf16x8*)(Wzb + (size_t)n*H_ + ks*32 + kc8*8);
      bf16x8 bW = *(const bf16x8*)(Whb + (size_t)n*H_ + ks*32 + kc8*8);
      #pragma unroll
      for (int r=0;r<2;r++){
        accZ[r][c] = __builtin_amdgcn_mfma_f32_16x16x32_bf16(aH[r], bZ, accZ[r][c], 0,0,0);
        accH[r][c] = __builtin_amdgcn_mfma_f32_16x16x32_bf16(aG[r], bW, accH[r][c], 0,0,0);
      }
    }
    __syncthreads();                              // prefetch done + reads done
    cur ^= 1;
  }

  // GRU epilogue. sumh re-read from global (L2-hot, just written by gather).
  #pragma unroll
  for (int r=0;r<2;r++){
    #pragma unroll
    for (int q=0;q<4;q++){
      int lm = wrow*32 + r*16 + kc8*4 + q;        // C/D: row=(lane>>4)*4+q
      int m  = m0 + lm;
      int mr = (m < M_) ? m : (M_ - 1);
      int v  = vmsg[mr];
      #pragma unroll
      for (int c=0;c<4;c++){
        int n = wcol*64 + c*16 + l16;
        float z   = sigm(tWz[v*H_ + n] + accZ[r][c][q]);
        float pre = tanh_(tWh[v*H_ + n] + accH[r][c][q]);
        float sh  = b2f(sumh[(size_t)mr*H_ + n]);
        float o   = (m == 0) ? 0.f : (1.f - z)*sh + z*pre;
        if (FIN){
          if (m < M_) hf[(size_t)m*H_ + n] = o;
        } else {
          u16 ob = f2b(o);
          lN[lds_off64(lm, n)] = ob;
          if (m < M_) dst[(size_t)m*HE_LD + ilv_h(n)] = ob;
        }
      }
    }
  }

  if (FIN) return;
  __syncthreads();   // h_new tile complete before E-GEMM A reads

  // E-GEMM: A from LDS h_new, B (Urb) direct from global.
  f32x4 accE[2][4];
  #pragma unroll
  for (int r=0;r<2;r++)
    #pragma unroll
    for (int c=0;c<4;c++)
      #pragma unroll
      for (int q=0;q<4;q++) accE[r][c][q] = 0.f;

  #pragma unroll
  for (int ks=0; ks<8; ++ks){
    bf16x8 aN[2];
    #pragma unroll
    for (int r=0;r<2;r++){
      int row = wrow*32 + r*16 + l16;
      int ao = row*256 + ((((ks*4 + kc8) ^ (row & 7)) << 3));
      aN[r] = *(const bf16x8*)&lN[ao];
    }
    #pragma unroll
    for (int c=0;c<4;c++){
      int n = wcol*64 + c*16 + l16;
      bf16x8 bU = *(const bf16x8*)(Urb + (size_t)n*H_ + ks*32 + kc8*8);
      #pragma unroll
      for (int r=0;r<2;r++)
        accE[r][c] = __builtin_amdgcn_mfma_f32_16x16x32_bf16(aN[r], bU, accE[r][c], 0,0,0);
    }
  }
  #pragma unroll
  for (int r=0;r<2;r++){
    #pragma unroll
    for (int q=0;q<4;q++){
      int m = m0 + wrow*32 + r*16 + kc8*4 + q;
      if (m >= M_) continue;
      #pragma unroll
      for (int c=0;c<4;c++){
        int n = wcol*64 + c*16 + l16;
        dst[(size_t)m*HE_LD + ilv_e(n)] = f2b(__expf(-accE[r][c][q]));
      }
    }
  }
}

// ---- Readout: only B=64 scope rows are needed. h f32 (final), out f32.
__global__ void k_final(const float* __restrict__ h, const int* __restrict__ ng,
                        const int* __restrict__ fnode, const int* __restrict__ scope,
                        const float* __restrict__ tWo, const float* __restrict__ Wo,
                        float* __restrict__ out){
  int b = blockIdx.x, j = threadIdx.x;
  int n = scope[b];
  __shared__ float mn[H_];
  float s = 0.f;
  #pragma unroll
  for (int k=0;k<K_;k++){
    int g = ng[n*K_ + k];
    s += h[(size_t)g*H_ + j];
  }
  mn[j] = s;
  __syncthreads();
  int v = fnode[n];
  float acc = tWo[v*H_ + j];
  const float* w = Wo + j*(2*H_) + H_;
  for (int i=0;i<H_;i+=4){
    float4 a = *(const float4*)(w+i);
    acc += mn[i]*a.x + mn[i+1]*a.y + mn[i+2]*a.z + mn[i+3]*a.w;
  }
  out[b*H_ + j] = fmaxf(acc, 0.f);
}

// ---- Guard signal: all-zero f32 output.
__global__ void k_zero(float* __restrict__ out, int n){
  int i = blockIdx.x*256 + threadIdx.x;
  int stride = gridDim.x*256;
  for (; i < n; i += stride) out[i] = 0.f;
}

extern "C" void kernel_launch(void* const* d_in, const int* in_sizes, int n_in,
                              void* d_out, int out_size, void* d_ws, size_t ws_size,
                              hipStream_t stream){
  const int* fnode      = (const int*)d_in[0];
  const int* fmess      = (const int*)d_in[1];
  const int* node_graph = (const int*)d_in[2];
  const int* mess_graph = (const int*)d_in[3];
  const int* scope_st   = (const int*)d_in[4];
  const float* emb = (const float*)d_in[5];
  const float* Wz  = (const float*)d_in[6];
  const float* bz  = (const float*)d_in[7];
  const float* Wr  = (const float*)d_in[8];
  const float* Ur  = (const float*)d_in[9];
  const float* bu  = (const float*)d_in[10];
  const float* Wh  = (const float*)d_in[11];
  const float* bh  = (const float*)d_in[12];
  const float* Wo  = (const float*)d_in[13];
  const float* bo  = (const float*)d_in[14];

  char* ws = (char*)d_ws;
  size_t off = 0;
  float* tWz = (float*)(ws + off); off += (size_t)V_*H_*4;
  float* tXr = (float*)(ws + off); off += (size_t)V_*H_*4;
  float* tWh = (float*)(ws + off); off += (size_t)V_*H_*4;
  float* tWo = (float*)(ws + off); off += (size_t)V_*H_*4;
  u16* Urb  = (u16*)(ws + off); off += (size_t)H_*H_*2;
  u16* Wzb  = (u16*)(ws + off); off += (size_t)H_*H_*2;
  u16* Whb  = (u16*)(ws + off); off += (size_t)H_*H_*2;
  int* vmsg = (int*)(ws + off); off += ((size_t)M_*4 + 1023) & ~(size_t)1023;
  u16* hA   = (u16*)(ws + off); off += (size_t)M_*H_*2;      // plain h1 (k_gemm A)
  u16* sumh = (u16*)(ws + off); off += (size_t)M_*H_*2;
  u16* sumg = (u16*)(ws + off); off += (size_t)M_*H_*2;

  if (ws_size < off){
    k_zero<<<2048, 256, 0, stream>>>((float*)d_out, out_size);
    return;
  }

  float* out = (float*)d_out;          // output dtype f32 (established R6)
  float* h   = out + (size_t)B_*H_;    // h (output 1) lives in d_out, f32
  // d_out's f32 h region (M*256*4 B) holds the packed bf16 hE buffer
  // (M*512*2 B -- exact same size) during iterations; the FIN k_gemmzh_e
  // overwrites it with f32 h (it reads only sumh/sumg/tables, no hazard).
  u16* hED = (u16*)h;

  const int MT64 = (M_ + 63)/64;       // 1563 row tiles (BM=64)
  const int GB   = (M_ + 7)/8;         // 12501 gather blocks (8 msgs each)

  k_tables<<<dim3(V_,4), H_, 0, stream>>>(emb, Wz, bz, Wr, bu, Wh, bh, Wo, bo,
                                          tWz, tXr, tWh, tWo);
  k_convw<<<H_, H_, 0, stream>>>(Ur, Wz, Wh, Urb, Wzb, Whb);
  k_init<<<M_, H_, 0, stream>>>(fnode, fmess, tWz, tWh, vmsg, hED, hA);
  k_gemm<<<MT64, 256, 0, stream>>>(hA, Urb, hED);   // E1 (once)

  for (int it = 0; it < DEPTH_-1; ++it){
    // Column-split gather: two sequential passes, each L3-resident (51 MB).
    k_gather2<<<GB, 256, 0, stream>>>(hED, mess_graph, vmsg, tXr, sumh, sumg, 0);
    k_gather2<<<GB, 256, 0, stream>>>(hED, mess_graph, vmsg, tXr, sumh, sumg, 1);
    if (it < DEPTH_-2)
      k_gemmzh_e<false><<<MT64, 512, 0, stream>>>(sumh, sumg, Wzb, Whb, Urb,
                                                  tWz, tWh, vmsg, hED, h);
    else
      k_gemmzh_e<true ><<<MT64, 512, 0, stream>>>(sumh, sumg, Wzb, Whb, Urb,
                                                  tWz, tWh, vmsg, hED, h);
  }

  k_final<<<B_, H_, 0, stream>>>(h, node_graph, fnode, scope_st, tWo, Wo, out);
}

// Round 8
// 1312.916 us; speedup vs baseline: 1.7842x; 1.5317x over previous
//
#include <hip/hip_runtime.h>

typedef unsigned short u16;
typedef unsigned int   u32;
typedef short bf16x8 __attribute__((ext_vector_type(8)));
typedef float f32x4  __attribute__((ext_vector_type(4)));

#define V_ 780
#define N_ 50000
#define M_ 100001
#define K_ 6
#define H_ 256
#define B_ 64
#define DEPTH_ 6

// hE packed row: 512 u16 = [h cols 0..255 | E cols 0..255], 1 KB per message.
// (Half-split, NOT interleaved: producers then write contiguous 512 B halves —
// R7's interleaved layout caused ~2x write amplification on the h/E stores.)
#define HE_LD 512

typedef __attribute__((address_space(3))) u32 lds_u32;
typedef __attribute__((address_space(1))) const u32 glb_u32;
__device__ __forceinline__ void dma16(const void* g, void* l){
  __builtin_amdgcn_global_load_lds((glb_u32*)g, (lds_u32*)l, 16, 0, 0);
}

__device__ __forceinline__ float b2f(u16 u){
  union { u32 i; float f; } x; x.i = ((u32)u) << 16; return x.f;
}
__device__ __forceinline__ u16 f2b(float f){
  union { float f; u32 i; } x; x.f = f;
  u32 r = x.i + 0x7fffu + ((x.i >> 16) & 1u);   // RNE
  return (u16)(r >> 16);
}
// v_rcp_f32 (~1 ulp) instead of precise-division sequence: bf16-negligible error.
__device__ __forceinline__ float rcp_(float x){ return __builtin_amdgcn_rcpf(x); }
__device__ __forceinline__ float sigm(float x){ return rcp_(1.f + __expf(-x)); }
__device__ __forceinline__ float tanh_(float x){
  x = fminf(fmaxf(x, -15.f), 15.f);
  float e = __expf(2.f*x);
  return (e - 1.f) * rcp_(e + 1.f);
}
__device__ __forceinline__ int swz(int r){ return (r + (r >> 2)) & 3; }

// ---- Per-vocab tables, f32-exact. Grid (V, 4): block = (vocab v, matrix q).
// q==1 stores tXr = exp(-(x@Wr.T + bu))  (gather consumes the exponential form).
__global__ void k_tables(const float* __restrict__ emb,
    const float* __restrict__ Wz, const float* __restrict__ bz,
    const float* __restrict__ Wr, const float* __restrict__ bu,
    const float* __restrict__ Wh, const float* __restrict__ bh,
    const float* __restrict__ Wo, const float* __restrict__ bo,
    float* __restrict__ tWz, float* __restrict__ tXr,
    float* __restrict__ tWh, float* __restrict__ tWo){
  int v = blockIdx.x, q = blockIdx.y, j = threadIdx.x;
  __shared__ float e[H_];
  e[j] = emb[v*H_ + j];
  __syncthreads();
  const float* w; const float* b; float* o; int ld;
  if      (q == 0){ w = Wz; b = bz; o = tWz; ld = 2*H_; }
  else if (q == 1){ w = Wr; b = bu; o = tXr; ld = H_;   }
  else if (q == 2){ w = Wh; b = bh; o = tWh; ld = 2*H_; }
  else            { w = Wo; b = bo; o = tWo; ld = 2*H_; }
  const float* wr = w + (size_t)j*ld;
  float a0 = 0.f, a1 = 0.f;
  #pragma unroll 4
  for (int i = 0; i < H_; i += 8){
    float4 x = *(const float4*)(wr + i);
    float4 y = *(const float4*)(wr + i + 4);
    a0 += e[i  ]*x.x + e[i+1]*x.y + e[i+2]*x.z + e[i+3]*x.w;
    a1 += e[i+4]*y.x + e[i+5]*y.y + e[i+6]*y.z + e[i+7]*y.w;
  }
  float val = a0 + a1 + b[j];
  if (q == 1) val = __expf(-val);
  o[v*H_ + j] = val;
}

// ---- Convert the three K-major 256x256 weight slices to bf16.
__global__ void k_convw(const float* __restrict__ Ur, const float* __restrict__ Wz,
                        const float* __restrict__ Wh,
                        u16* __restrict__ Urb, u16* __restrict__ Wzb, u16* __restrict__ Whb){
  int r = blockIdx.x, j = threadIdx.x;
  Urb[r*H_ + j] = f2b(Ur[r*H_ + j]);
  Wzb[r*H_ + j] = f2b(Wz[r*(2*H_) + H_ + j]);   // columns H..2H of Wz row r
  Whb[r*H_ + j] = f2b(Wh[r*(2*H_) + H_ + j]);
}

// ---- vmsg[m] = fnode[fmess[m]]; h1 closed form (h0=0), bf16, masked at m==0.
// Writes into the h half of the packed hE row.
__global__ void k_init(const int* __restrict__ fnode, const int* __restrict__ fmess,
                       const float* __restrict__ tWz, const float* __restrict__ tWh,
                       int* __restrict__ vmsg, u16* __restrict__ hE){
  int m = blockIdx.x, j = threadIdx.x;
  int v = fnode[fmess[m]];
  if (j == 0) vmsg[m] = v;
  float val = (m == 0) ? 0.f : sigm(tWz[v*H_ + j])*tanh_(tWh[v*H_ + j]);
  hE[(size_t)m*HE_LD + j] = f2b(val);
}

// ---- Neighbor gather + reduce from packed hE rows: sum_h and sum_gated.
// R3's exact kernel (measured 107-109 us = random-access floor). One wave per
// message; lane l owns cols 4l..4l+3; barrier-free, ~32 VGPR, high occupancy.
// sigm(xr+u) = rcp(fma(X, E, 1)): X = tXr[v,:] (f32), E = exp(-hUr) (bf16).
__global__ void k_gather(const u16* __restrict__ hE,
                         const int* __restrict__ mg, const int* __restrict__ vmsg,
                         const float* __restrict__ tXr,
                         u16* __restrict__ sumh, u16* __restrict__ sumg){
  int m = blockIdx.x*4 + (threadIdx.x >> 6);
  if (m >= M_) return;
  const int lane = threadIdx.x & 63;
  int v = vmsg[m];
  float4 X = *(const float4*)(tXr + (size_t)v*H_ + lane*4);
  const int2* mgp = (const int2*)(mg + m*K_);   // m*24 B is 8-aligned
  int2 g01 = mgp[0], g23 = mgp[1], g45 = mgp[2];
  int gs[K_] = {g01.x, g01.y, g23.x, g23.y, g45.x, g45.y};
  const char* bc = (const char*)hE;
  const u32 cb = (u32)lane * 8u;
  float s0=0.f,s1=0.f,s2=0.f,s3=0.f, a0=0.f,a1=0.f,a2=0.f,a3=0.f;
  #pragma unroll
  for (int k=0;k<K_;k++){
    u32 off = ((u32)gs[k] << 10) + cb;          // 32-bit byte offset (<103 MB)
    uint2 hp = *(const uint2*)(bc + off);        // h cols 4l..4l+3
    uint2 ep = *(const uint2*)(bc + off + 512);  // E cols 4l..4l+3
    float h0=b2f((u16)hp.x), h1=b2f((u16)(hp.x>>16));
    float h2=b2f((u16)hp.y), h3=b2f((u16)(hp.y>>16));
    float e0=b2f((u16)ep.x), e1=b2f((u16)(ep.x>>16));
    float e2=b2f((u16)ep.y), e3=b2f((u16)(ep.y>>16));
    s0+=h0; s1+=h1; s2+=h2; s3+=h3;
    a0 += rcp_(fmaf(X.x,e0,1.f))*h0;
    a1 += rcp_(fmaf(X.y,e1,1.f))*h1;
    a2 += rcp_(fmaf(X.z,e2,1.f))*h2;
    a3 += rcp_(fmaf(X.w,e3,1.f))*h3;
  }
  uint2 sh, sg;
  sh.x = (u32)f2b(s0) | ((u32)f2b(s1)<<16);
  sh.y = (u32)f2b(s2) | ((u32)f2b(s3)<<16);
  sg.x = (u32)f2b(a0) | ((u32)f2b(a1)<<16);
  sg.y = (u32)f2b(a2) | ((u32)f2b(a3)<<16);
  *(uint2*)((char*)sumh + ((size_t)m<<9) + cb) = sh;
  *(uint2*)((char*)sumg + ((size_t)m<<9) + cb) = sg;
}

// ---- E half of hE = exp(-(h @ Ur.T)). The R0-baseline shape that measured
// ~33 us: BM=128, BN=256, 512 thr, full-drain per K-step, 24 KB LDS,
// acc=64 floats -> ~124 unified regs -> 2 blk x 8 waves = 50% occupancy.
// Reads h half (stride 512), writes E half. Disjoint halves -> no hazard.
__global__ __launch_bounds__(512,4) void k_gemmE(
    const u16* hE, const u16* __restrict__ W){
  __shared__ __align__(16) u16 lA[128*32];
  __shared__ __align__(16) u16 lB[256*32];
  const int t    = threadIdx.x;
  const int m0   = blockIdx.x * 128;
  const int lane = t & 63, wave = t >> 6;     // 8 waves: 2 x 4
  const int wrow = wave >> 2, wcol = wave & 3;
  const int l16  = lane & 15, kc8 = lane >> 4;

  // A: 512 slots, 1/thread. slot s=(row,cc): global chunk kc = cc ^ swz(row).
  const int rA = t >> 2, cA = t & 3;
  const int kA = (cA ^ swz(rA)) * 8;
  const int gmA = (m0 + rA < M_) ? (m0 + rA) : (M_ - 1);
  u16* const dA = lA + (size_t)(wave*64)*8;   // wave-uniform LDS base
  // B: 1024 slots, 2/thread.
  int rB[2], kB[2];
  u16* dB[2];
  #pragma unroll
  for (int p=0;p<2;p++){
    int s = t + 512*p;
    rB[p] = s >> 2; int cB = s & 3;
    kB[p] = (cB ^ swz(rB[p])) * 8;
    dB[p] = lB + (size_t)(wave*64 + 512*p)*8;
  }

  f32x4 acc[4][4];
  #pragma unroll
  for (int r=0;r<4;r++)
    #pragma unroll
    for (int c=0;c<4;c++)
      #pragma unroll
      for (int q=0;q<4;q++) acc[r][c][q] = 0.f;

  for (int k0=0; k0<H_; k0+=32){
    __syncthreads();
    dma16(hE + (size_t)gmA*HE_LD + k0 + kA, dA);
    #pragma unroll
    for (int p=0;p<2;p++)
      dma16(W + (size_t)rB[p]*H_ + k0 + kB[p], dB[p]);
    __syncthreads();                          // drains vmcnt -> DMA complete
    bf16x8 aF[4], bF[4];
    #pragma unroll
    for (int r=0;r<4;r++){
      int row = wrow*64 + r*16 + l16;
      aF[r] = *(const bf16x8*)(&lA[row*32 + ((kc8 ^ swz(row))*8)]);
    }
    #pragma unroll
    for (int c=0;c<4;c++){
      int row = wcol*64 + c*16 + l16;
      bF[c] = *(const bf16x8*)(&lB[row*32 + ((kc8 ^ swz(row))*8)]);
    }
    #pragma unroll
    for (int r=0;r<4;r++)
      #pragma unroll
      for (int c=0;c<4;c++)
        acc[r][c] = __builtin_amdgcn_mfma_f32_16x16x32_bf16(aF[r], bF[c], acc[r][c], 0,0,0);
  }

  u16* C = (u16*)hE;
  #pragma unroll
  for (int r=0;r<4;r++){
    #pragma unroll
    for (int c=0;c<4;c++){
      int mb = m0 + wrow*64 + r*16 + kc8*4;   // C/D: row=(lane>>4)*4+reg
      int n  = wcol*64 + c*16 + l16;          //      col=lane&15
      #pragma unroll
      for (int q=0;q<4;q++){
        int m = mb + q;
        if (m < M_) C[(size_t)m*HE_LD + H_ + n] = f2b(__expf(-acc[r][c][q]));
      }
    }
  }
}

// ---- Dual GEMM (z, pre-h) + GRU epilogue, in the same high-occupancy shape:
// BM=128, BN=128, 512 thr (8 waves = 4x2, wave-tile 32x64), full-drain,
// 32 KB LDS, dual acc = 64 floats -> ~120 unified regs -> 2 blk = 50% occ.
// (R0's gemmzh died at 195us with 128 acc + 108 arch = 236 regs -> 8 waves/CU.)
// FIN: write f32 h (stride 256); else bf16 h into the hE h-half (stride 512).
template<bool FIN>
__global__ __launch_bounds__(512,4) void k_gemmzh(
    const u16* __restrict__ sumh, const u16* __restrict__ sumg,
    const u16* __restrict__ Wzb, const u16* __restrict__ Whb,
    const float* __restrict__ tWz, const float* __restrict__ tWh,
    const int* __restrict__ vmsg,
    u16* __restrict__ dst, float* __restrict__ hf){
  __shared__ __align__(16) u16 lH[128*32];
  __shared__ __align__(16) u16 lG[128*32];
  __shared__ __align__(16) u16 lZ[128*32];
  __shared__ __align__(16) u16 lW[128*32];
  const int t    = threadIdx.x;
  const int m0   = (blockIdx.x >> 1) * 128;
  const int n0   = (blockIdx.x & 1) * 128;
  const int lane = t & 63, wave = t >> 6;
  const int wrow = wave >> 1, wcol = wave & 1;   // 4 x 2 -> wave-tile 32x64
  const int l16  = lane & 15, kc8 = lane >> 4;

  // Staging: 512 slots per matrix, 1 slot/thread/matrix (4 dma16 per step).
  const int rS = t >> 2, cS = t & 3;
  const int kS = (cS ^ swz(rS)) * 8;
  const int gmS = (m0 + rS < M_) ? (m0 + rS) : (M_ - 1);
  const int gnS = n0 + rS;
  const int dOff = (wave*64)*8;                  // wave-uniform LDS base

  f32x4 accZ[2][4], accH[2][4];
  #pragma unroll
  for (int r=0;r<2;r++)
    #pragma unroll
    for (int c=0;c<4;c++)
      #pragma unroll
      for (int q=0;q<4;q++){ accZ[r][c][q]=0.f; accH[r][c][q]=0.f; }

  for (int k0=0; k0<H_; k0+=32){
    __syncthreads();
    dma16(sumh + (size_t)gmS*H_ + k0 + kS, lH + dOff);
    dma16(sumg + (size_t)gmS*H_ + k0 + kS, lG + dOff);
    dma16(Wzb  + (size_t)gnS*H_ + k0 + kS, lZ + dOff);
    dma16(Whb  + (size_t)gnS*H_ + k0 + kS, lW + dOff);
    __syncthreads();                             // drains vmcnt -> DMA complete
    bf16x8 aH[2], aG[2];
    #pragma unroll
    for (int r=0;r<2;r++){
      int row = wrow*32 + r*16 + l16;
      int ao = row*32 + ((kc8 ^ swz(row))*8);
      aH[r] = *(const bf16x8*)&lH[ao];
      aG[r] = *(const bf16x8*)&lG[ao];
    }
    #pragma unroll
    for (int c=0;c<4;c++){
      int row = wcol*64 + c*16 + l16;
      int bo = row*32 + ((kc8 ^ swz(row))*8);
      bf16x8 bZ = *(const bf16x8*)&lZ[bo];
      bf16x8 bW = *(const bf16x8*)&lW[bo];
      #pragma unroll
      for (int r=0;r<2;r++){
        accZ[r][c] = __builtin_amdgcn_mfma_f32_16x16x32_bf16(aH[r], bZ, accZ[r][c], 0,0,0);
        accH[r][c] = __builtin_amdgcn_mfma_f32_16x16x32_bf16(aG[r], bW, accH[r][c], 0,0,0);
      }
    }
  }

  // GRU epilogue. sumh element re-read from global (L3/L2-warm).
  #pragma unroll
  for (int r=0;r<2;r++){
    #pragma unroll
    for (int q=0;q<4;q++){
      int m  = m0 + wrow*32 + r*16 + kc8*4 + q;  // C/D: row=(lane>>4)*4+q
      int mr = (m < M_) ? m : (M_ - 1);
      int v  = vmsg[mr];
      #pragma unroll
      for (int c=0;c<4;c++){
        int n = n0 + wcol*64 + c*16 + l16;
        float z   = sigm(tWz[v*H_ + n] + accZ[r][c][q]);
        float pre = tanh_(tWh[v*H_ + n] + accH[r][c][q]);
        float sh  = b2f(sumh[(size_t)mr*H_ + n]);
        float o   = (m == 0) ? 0.f : (1.f - z)*sh + z*pre;
        if (m < M_){
          if (FIN) hf[(size_t)m*H_ + n] = o;
          else     dst[(size_t)m*HE_LD + n] = f2b(o);
        }
      }
    }
  }
}

// ---- Readout: only B=64 scope rows are needed. h f32 (final), out f32.
__global__ void k_final(const float* __restrict__ h, const int* __restrict__ ng,
                        const int* __restrict__ fnode, const int* __restrict__ scope,
                        const float* __restrict__ tWo, const float* __restrict__ Wo,
                        float* __restrict__ out){
  int b = blockIdx.x, j = threadIdx.x;
  int n = scope[b];
  __shared__ float mn[H_];
  float s = 0.f;
  #pragma unroll
  for (int k=0;k<K_;k++){
    int g = ng[n*K_ + k];
    s += h[(size_t)g*H_ + j];
  }
  mn[j] = s;
  __syncthreads();
  int v = fnode[n];
  float acc = tWo[v*H_ + j];
  const float* w = Wo + j*(2*H_) + H_;
  for (int i=0;i<H_;i+=4){
    float4 a = *(const float4*)(w+i);
    acc += mn[i]*a.x + mn[i+1]*a.y + mn[i+2]*a.z + mn[i+3]*a.w;
  }
  out[b*H_ + j] = fmaxf(acc, 0.f);
}

// ---- Guard signal: all-zero f32 output.
__global__ void k_zero(float* __restrict__ out, int n){
  int i = blockIdx.x*256 + threadIdx.x;
  int stride = gridDim.x*256;
  for (; i < n; i += stride) out[i] = 0.f;
}

extern "C" void kernel_launch(void* const* d_in, const int* in_sizes, int n_in,
                              void* d_out, int out_size, void* d_ws, size_t ws_size,
                              hipStream_t stream){
  const int* fnode      = (const int*)d_in[0];
  const int* fmess      = (const int*)d_in[1];
  const int* node_graph = (const int*)d_in[2];
  const int* mess_graph = (const int*)d_in[3];
  const int* scope_st   = (const int*)d_in[4];
  const float* emb = (const float*)d_in[5];
  const float* Wz  = (const float*)d_in[6];
  const float* bz  = (const float*)d_in[7];
  const float* Wr  = (const float*)d_in[8];
  const float* Ur  = (const float*)d_in[9];
  const float* bu  = (const float*)d_in[10];
  const float* Wh  = (const float*)d_in[11];
  const float* bh  = (const float*)d_in[12];
  const float* Wo  = (const float*)d_in[13];
  const float* bo  = (const float*)d_in[14];

  char* ws = (char*)d_ws;
  size_t off = 0;
  float* tWz = (float*)(ws + off); off += (size_t)V_*H_*4;
  float* tXr = (float*)(ws + off); off += (size_t)V_*H_*4;
  float* tWh = (float*)(ws + off); off += (size_t)V_*H_*4;
  float* tWo = (float*)(ws + off); off += (size_t)V_*H_*4;
  u16* Urb  = (u16*)(ws + off); off += (size_t)H_*H_*2;
  u16* Wzb  = (u16*)(ws + off); off += (size_t)H_*H_*2;
  u16* Whb  = (u16*)(ws + off); off += (size_t)H_*H_*2;
  int* vmsg = (int*)(ws + off); off += ((size_t)M_*4 + 1023) & ~(size_t)1023;
  u16* sumh = (u16*)(ws + off); off += (size_t)M_*H_*2;
  u16* sumg = (u16*)(ws + off); off += (size_t)M_*H_*2;

  if (ws_size < off){
    k_zero<<<2048, 256, 0, stream>>>((float*)d_out, out_size);
    return;
  }

  float* out = (float*)d_out;          // output dtype f32 (established R6)
  float* h   = out + (size_t)B_*H_;    // h (output 1) lives in d_out, f32
  // d_out's f32 h region (M*256*4 B) holds the packed bf16 hE buffer
  // (M*512*2 B -- exact same size) during iterations; the FIN k_gemmzh
  // overwrites it with f32 h (it reads only sums/tables -> no hazard).
  u16* hE = (u16*)h;

  const int MT128 = (M_ + 127)/128;    // 782 row tiles (BM=128)
  const int GG    = 2*MT128;           // gemmzh: x2 col tiles
  const int GB    = (M_ + 3)/4;        // gather blocks (4 msgs each)

  k_tables<<<dim3(V_,4), H_, 0, stream>>>(emb, Wz, bz, Wr, bu, Wh, bh, Wo, bo,
                                          tWz, tXr, tWh, tWo);
  k_convw<<<H_, H_, 0, stream>>>(Ur, Wz, Wh, Urb, Wzb, Whb);
  k_init<<<M_, H_, 0, stream>>>(fnode, fmess, tWz, tWh, vmsg, hE);
  k_gemmE<<<MT128, 512, 0, stream>>>(hE, Urb);   // E1

  for (int it = 0; it < DEPTH_-1; ++it){
    k_gather<<<GB, 256, 0, stream>>>(hE, mess_graph, vmsg, tXr, sumh, sumg);
    if (it < DEPTH_-2){
      k_gemmzh<false><<<GG, 512, 0, stream>>>(sumh, sumg, Wzb, Whb,
                                              tWz, tWh, vmsg, hE, h);
      k_gemmE<<<MT128, 512, 0, stream>>>(hE, Urb);
    } else {
      k_gemmzh<true ><<<GG, 512, 0, stream>>>(sumh, sumg, Wzb, Whb,
                                              tWz, tWh, vmsg, hE, h);
    }
  }

  k_final<<<B_, H_, 0, stream>>>(h, node_graph, fnode, scope_st, tWo, Wo, out);
}